// Round 4
// baseline (243.931 us; speedup 1.0000x reference)
//
#include <hip/hip_runtime.h>

// MovementEmbeddingModule: bs=4, d=16, K=10, C=3, h=w=128
// out: (4, 60, 16, 128, 128) f32; out[b][k*6+c][d][y][x]
#define BS 4
#define DD 16
#define KK 10
#define CC 3
#define HH 128
#define WW 128
#define HW   (HH*WW)            // 16384
#define CHW  (CC*HW)            // 49152
#define IMG_FLOATS (BS*CHW)     // 196608
#define PAD_FLOATS 24576        // 96 KB guard each side (covers +-66 KB excursion)
#define WS_NEED ((size_t)(IMG_FLOATS + 2*PAD_FLOATS) * 4)

using f4 = __attribute__((ext_vector_type(4))) float;

// 4-byte-aligned 16B chunk (source col base is icx+4*xg: dword- but not 16B-aligned)
struct F4U { float v[4]; };

__global__ __launch_bounds__(256) void img_pad_copy(
    const float* __restrict__ img, float* __restrict__ dst)
{
    const int i = (int)(blockIdx.x * 256u + threadIdx.x) * 4;
    *(f4*)(dst + i) = *(const f4*)(img + i);
}

// PADDED: src points at ws+PAD_FLOATS holding a copy of img with guard pads ->
// hot path has NO address clamping (OOB elements are garbage, zeroed by masks).
// !PADDED fallback: per-element clamped scalar loads straight from img.
template<bool PADDED>
__global__ __launch_bounds__(256) void movement_embed_kernel(
    const float* __restrict__ kp_app,   // (4,1,10,2)
    const float* __restrict__ kp_vid,   // (4,16,10,2)
    const float* __restrict__ src,
    float* __restrict__ out)
{
    const unsigned bi  = blockIdx.x;
    const unsigned sub = bi & 15u;          // 16 row-tiles (8 rows each) per (b,d,k)
    const unsigned bdk = bi >> 4;
    const unsigned k   = bdk % KK;
    const unsigned t2  = bdk / KK;
    const unsigned d   = t2 % DD;
    const unsigned b   = t2 / DD;

    const int tid = (int)threadIdx.x;
    const int xg  = tid & 31;               // float4 column
    const int ly  = tid >> 5;               // local row 0..7
    const int x4  = xg * 4;
    const int y   = (int)(sub * 8u) + ly;

    // wave-uniform keypoint math (SGPR path)
    const float kvx  = kp_vid[((b*DD + d)*KK + k)*2 + 0];
    const float kvy  = kp_vid[((b*DD + d)*KK + k)*2 + 1];
    const float kv0x = kp_vid[((b*DD + 0)*KK + k)*2 + 0];
    const float kv0y = kp_vid[((b*DD + 0)*KK + k)*2 + 1];
    const float kax  = kp_app[(b*KK + k)*2 + 0];
    const float kay  = kp_app[(b*KK + k)*2 + 1];

    const float diffx = kvx - kv0x;     // exactly 0 at d==0
    const float diffy = kvy - kv0y;
    const float mx = diffx + kax;       // heatmap center
    const float my = diffy + kay;
    const float vdx = -diffx;           // kp_video_diff (diff-map consts + warp shift)
    const float vdy = -diffy;

    // Uniform bilinear decomposition: sample coord = pixel + c (step*(W-1)/2 == 1.0)
    const float cx = vdx * 63.5f;
    const float cy = vdy * 63.5f;
    const float fcx = floorf(cx), fcy = floorf(cy);
    const int icx = (int)fcx, icy = (int)fcy;
    const float wx1 = cx - fcx, wx0 = 1.0f - wx1;   // block-uniform weights
    const float wy1 = cy - fcy, wy0 = 1.0f - wy1;

    const int r0   = y + icy;           // top source row (unclamped)
    const int col0 = icx + x4;          // left source col of element 0 (unclamped)
    const bool rv0 = (unsigned)r0       < (unsigned)HH;
    const bool rv1 = (unsigned)(r0 + 1) < (unsigned)HH;
    bool cv[5];
#pragma unroll
    for (int e = 0; e < 5; ++e) cv[e] = (unsigned)(col0 + e) < (unsigned)WW;

    // ---- heatmap (no load dependence) ----
    const float step = 2.0f / 127.0f;
    const float gy  = (float)y  * step - 1.0f;
    const float gx0 = (float)x4 * step - 1.0f;
    const float dy1 = gy - my, dy0 = gy - kay;
    const float dy1sq = dy1 * dy1, dy0sq = dy0 * dy0;
    float hvv[4];
#pragma unroll
    for (int j = 0; j < 4; ++j) {
        const float gx = gx0 + (float)j * step;
        const float dx1 = gx - mx, dx0 = gx - kax;
        hvv[j] = __expf(-50.0f * (dx1 * dx1 + dy1sq))
               - __expf(-50.0f * (dx0 * dx0 + dy0sq));
    }

    // ---- stores: out[b][k*6+c][d][y][x] ----
    const size_t chs  = (size_t)DD * HW;   // 262144
    const size_t base = ((((size_t)b * (KK * 6) + k * 6) * DD + d) * HH + y) * WW + (size_t)x4;

    // 3 load-independent channel stores first (overlap gather latency)
    {
        f4 H;  H.x = hvv[0]; H.y = hvv[1]; H.z = hvv[2]; H.w = hvv[3];
        *(f4*)(out + base) = H;
        f4 VX; VX.x = vdx; VX.y = vdx; VX.z = vdx; VX.w = vdx;
        *(f4*)(out + base + chs) = VX;
        f4 VY; VY.x = vdy; VY.y = vdy; VY.z = vdy; VY.w = vdy;
        *(f4*)(out + base + 2 * chs) = VY;
    }

    // ---- deformed: direct per-thread bilinear gather (no LDS, no fences) ----
#pragma unroll
    for (int c = 0; c < CC; ++c) {
        float a0[5], a1[5];
        if constexpr (PADDED) {
            const long idx = (long)b * CHW + (long)c * HW + (long)r0 * WW + (long)col0;
            const float* p = src + idx;            // may dip into guard pads: safe
            const F4U A  = *(const F4U*)p;
            const float a4 = p[4];
            const F4U Bt = *(const F4U*)(p + WW);
            const float b4 = p[WW + 4];
#pragma unroll
            for (int e = 0; e < 4; ++e) { a0[e] = A.v[e]; a1[e] = Bt.v[e]; }
            a0[4] = a4; a1[4] = b4;
        } else {
            const int rc0 = min(max(r0, 0), HH - 1);
            const int rc1 = min(max(r0 + 1, 0), HH - 1);
            const int cb  = b * CHW + c * HW;
#pragma unroll
            for (int e = 0; e < 5; ++e) {
                const int cc = min(max(col0 + e, 0), WW - 1);
                a0[e] = src[cb + rc0 * WW + cc];
                a1[e] = src[cb + rc1 * WW + cc];
            }
        }
        // zero-padding masks (select, not multiply: pad garbage may be NaN)
#pragma unroll
        for (int e = 0; e < 5; ++e) {
            a0[e] = (rv0 && cv[e]) ? a0[e] : 0.0f;
            a1[e] = (rv1 && cv[e]) ? a1[e] : 0.0f;
        }
        float dvv[4];
#pragma unroll
        for (int e = 0; e < 4; ++e) {
            const float h0 = wx0 * a0[e] + wx1 * a0[e + 1];
            const float h1 = wx0 * a1[e] + wx1 * a1[e + 1];
            dvv[e] = wy0 * h0 + wy1 * h1;
        }
        f4 DV; DV.x = dvv[0]; DV.y = dvv[1]; DV.z = dvv[2]; DV.w = dvv[3];
        *(f4*)(out + base + (size_t)(3 + c) * chs) = DV;
    }
}

extern "C" void kernel_launch(void* const* d_in, const int* in_sizes, int n_in,
                              void* d_out, int out_size, void* d_ws, size_t ws_size,
                              hipStream_t stream) {
    const float* kp_app = (const float*)d_in[0];   // (4,1,10,2)
    const float* kp_vid = (const float*)d_in[1];   // (4,16,10,2)
    const float* img    = (const float*)d_in[2];   // (4,3,1,128,128)
    float* out = (float*)d_out;                    // (4,60,16,128,128)

    const int nblocks = BS * DD * KK * 16;         // 10240

    if (d_ws != nullptr && ws_size >= WS_NEED) {
        float* wimg = (float*)d_ws;
        img_pad_copy<<<IMG_FLOATS / (256 * 4), 256, 0, stream>>>(img, wimg + PAD_FLOATS);
        movement_embed_kernel<true><<<nblocks, 256, 0, stream>>>(
            kp_app, kp_vid, wimg + PAD_FLOATS, out);
    } else {
        movement_embed_kernel<false><<<nblocks, 256, 0, stream>>>(
            kp_app, kp_vid, img, out);
    }
}